// Round 1
// baseline (610.418 us; speedup 1.0000x reference)
//
#include <hip/hip_runtime.h>

// Problem constants (fixed by reference)
#define B_ROWS 8192
#define E_DIM  256
#define H_DIM  4096

typedef __attribute__((ext_vector_type(8))) short short8;
typedef __attribute__((ext_vector_type(4))) float f32x4;

typedef __attribute__((address_space(1))) const void* gas1_t;
typedef __attribute__((address_space(3))) void*       las3_t;

__device__ __forceinline__ float b2f(unsigned short s) {
    return __uint_as_float(((unsigned)s) << 16);
}
__device__ __forceinline__ unsigned short f2b(float f) {
    unsigned u = __float_as_uint(f);
    u += 0x7fffu + ((u >> 16) & 1u);   // RNE
    return (unsigned short)(u >> 16);
}

// ---------------------------------------------------------------------------
// Transpose + cast f32 [R,C] -> bf16 [C,R]   (makes W k-contiguous for MFMA)
// grid (C/32, R/32), block 256
__global__ void k_transpose_cast(const float* __restrict__ in,
                                 unsigned short* __restrict__ out,
                                 int R, int C) {
    __shared__ float tile[32][33];
    const int c0 = blockIdx.x * 32, r0 = blockIdx.y * 32;
    const int tx = threadIdx.x & 31, ty = threadIdx.x >> 5;  // ty 0..7
#pragma unroll
    for (int j = 0; j < 4; ++j)
        tile[ty * 4 + j][tx] = in[(size_t)(r0 + ty * 4 + j) * C + c0 + tx];
    __syncthreads();
#pragma unroll
    for (int j = 0; j < 4; ++j)
        out[(size_t)(c0 + ty * 4 + j) * R + r0 + tx] = f2b(tile[tx][ty * 4 + j]);
}

// ---------------------------------------------------------------------------
// Cast f32 -> bf16, 4 elems/thread. grid n/(4*256)
__global__ void k_cast_bf16(const float* __restrict__ in,
                            unsigned short* __restrict__ out, int n4) {
    int i = blockIdx.x * blockDim.x + threadIdx.x;
    if (i < n4) {
        float4 v = ((const float4*)in)[i];
        ushort4 o;
        o.x = f2b(v.x); o.y = f2b(v.y); o.z = f2b(v.z); o.w = f2b(v.w);
        ((ushort4*)out)[i] = o;
    }
}

// ---------------------------------------------------------------------------
// bf16 MFMA GEMM: C[M,N] = A[M,K] * Bt[N,K]^T  (both operands k-contiguous)
// m97-style: BK=32, 4 waves as 2x2, global_load_lds width 16, single buffer.
template <int BM, int BN, bool OUT_BF16, bool ADD_BIAS>
__global__ __launch_bounds__(256) void k_gemm_bt(
    const unsigned short* __restrict__ A, const unsigned short* __restrict__ Bt,
    void* __restrict__ Cout, const float* __restrict__ bias,
    int M, int N, int K) {
    constexpr int BK = 32;
    constexpr int MI = BM / 32, NI = BN / 32;
    __shared__ __align__(16) short As[BM * BK];
    __shared__ __align__(16) short Bs[BN * BK];

    const int t = threadIdx.x;
    const int lane = t & 63, wv = t >> 6;
    const int wr = wv >> 1, wc = wv & 1;
    const int l15 = lane & 15, quad = lane >> 4;
    const int m0 = blockIdx.y * BM, n0 = blockIdx.x * BN;

    f32x4 acc[MI][NI] = {};

    for (int k0 = 0; k0 < K; k0 += BK) {
        // stage A tile: BM rows x 32 k (64B/row), 16B per lane
#pragma unroll
        for (int q = 0; q < (BM * 4) / 256; ++q) {
            int u = q * 256 + t;
            const short* gp = (const short*)A + (size_t)(m0 + (u >> 2)) * K + k0 + (u & 3) * 8;
            short* lp = As + (size_t)(q * 256 + (wv << 6)) * 8;  // wave-uniform base
            __builtin_amdgcn_global_load_lds((gas1_t)gp, (las3_t)lp, 16, 0, 0);
        }
#pragma unroll
        for (int q = 0; q < (BN * 4) / 256; ++q) {
            int u = q * 256 + t;
            const short* gp = (const short*)Bt + (size_t)(n0 + (u >> 2)) * K + k0 + (u & 3) * 8;
            short* lp = Bs + (size_t)(q * 256 + (wv << 6)) * 8;
            __builtin_amdgcn_global_load_lds((gas1_t)gp, (las3_t)lp, 16, 0, 0);
        }
        __syncthreads();

        short8 af[MI], bfr[NI];
#pragma unroll
        for (int mi = 0; mi < MI; ++mi)
            af[mi] = *(const short8*)(As + (wr * (BM / 2) + mi * 16 + l15) * BK + quad * 8);
#pragma unroll
        for (int ni = 0; ni < NI; ++ni)
            bfr[ni] = *(const short8*)(Bs + (wc * (BN / 2) + ni * 16 + l15) * BK + quad * 8);
#pragma unroll
        for (int mi = 0; mi < MI; ++mi)
#pragma unroll
            for (int ni = 0; ni < NI; ++ni)
                acc[mi][ni] = __builtin_amdgcn_mfma_f32_16x16x32_bf16(
                    af[mi], bfr[ni], acc[mi][ni], 0, 0, 0);
        __syncthreads();
    }

    // epilogue: C/D layout col=lane&15, row=quad*4+reg (measured m89)
#pragma unroll
    for (int mi = 0; mi < MI; ++mi)
#pragma unroll
        for (int ni = 0; ni < NI; ++ni)
#pragma unroll
            for (int r = 0; r < 4; ++r) {
                int row = m0 + wr * (BM / 2) + mi * 16 + quad * 4 + r;
                int col = n0 + wc * (BN / 2) + ni * 16 + l15;
                float v = acc[mi][ni][r];
                if (ADD_BIAS) v += bias[col];
                if (OUT_BF16)
                    ((unsigned short*)Cout)[(size_t)row * N + col] = f2b(v);
                else
                    ((float*)Cout)[(size_t)row * N + col] = v;
            }
}

// ---------------------------------------------------------------------------
// Column sums / sumsq of bf16 h [B_ROWS, H_DIM]. grid (16,64) block 256.
__global__ void k_colstats(const unsigned short* __restrict__ h,
                           float* __restrict__ sum, float* __restrict__ sumsq) {
    const int col = blockIdx.x * 256 + threadIdx.x;
    const int r0 = blockIdx.y * 128;
    float s = 0.f, s2 = 0.f;
    for (int r = 0; r < 128; ++r) {
        float v = b2f(h[(size_t)(r0 + r) * H_DIM + col]);
        s += v; s2 += v * v;
    }
    atomicAdd(&sum[col], s);
    atomicAdd(&sumsq[col], s2);
}

// BN scale/shift: scale = gamma*rsqrt(var+eps), shift = beta - mu*scale
__global__ void k_bnprep(const float* __restrict__ sum, const float* __restrict__ sumsq,
                         const float* __restrict__ gamma, const float* __restrict__ beta,
                         float* __restrict__ scale, float* __restrict__ shift) {
    int j = blockIdx.x * 256 + threadIdx.x;
    float mu = sum[j] * (1.f / B_ROWS);
    float var = sumsq[j] * (1.f / B_ROWS) - mu * mu;
    float sc = gamma[j] * rsqrtf(var + 1e-5f);
    scale[j] = sc;
    shift[j] = beta[j] - mu * sc;
}

// h := relu(h*scale + shift), 8 bf16 per thread. grid B*H/8/256
__global__ void k_bnrelu(unsigned short* __restrict__ h,
                         const float* __restrict__ scale,
                         const float* __restrict__ shift) {
    size_t i8 = (size_t)blockIdx.x * 256 + threadIdx.x;
    int c0 = (int)((i8 * 8) & (H_DIM - 1));
    uint4 d = ((uint4*)h)[i8];
    unsigned short* u = (unsigned short*)&d;
#pragma unroll
    for (int j = 0; j < 8; ++j) {
        float v = b2f(u[j]) * scale[c0 + j] + shift[c0 + j];
        u[j] = f2b(fmaxf(v, 0.f));
    }
    ((uint4*)h)[i8] = d;
}

// ---------------------------------------------------------------------------
// Row inverse-norms of 4 [B,256] f32 arrays. grid (B/4, 4), 1 wave/row.
__global__ void k_rownorm4(const float* __restrict__ a0, const float* __restrict__ a1,
                           const float* __restrict__ a2, const float* __restrict__ a3,
                           float* __restrict__ o0, float* __restrict__ o1,
                           float* __restrict__ o2, float* __restrict__ o3) {
    int which = blockIdx.y;
    const float* x = which == 0 ? a0 : which == 1 ? a1 : which == 2 ? a2 : a3;
    float* inv = which == 0 ? o0 : which == 1 ? o1 : which == 2 ? o2 : o3;
    int row = blockIdx.x * 4 + (threadIdx.x >> 6);
    int lane = threadIdx.x & 63;
    float4 v = ((const float4*)(x + (size_t)row * E_DIM))[lane];
    float s = v.x * v.x + v.y * v.y + v.z * v.z + v.w * v.w;
#pragma unroll
    for (int o = 32; o; o >>= 1) s += __shfl_down(s, o);
    if (lane == 0) inv[row] = 1.f / fmaxf(sqrtf(s), 1e-12f);
}

// ---------------------------------------------------------------------------
// Gram: Mout[a][b] += sum_i P[i,a]*Q[i,b]*invP[i]*invQ[i]
// grid (4,4,16): z = mec*8 + kchunk (chunks of 1024 rows). atomic split-K.
#define KS 8
__global__ __launch_bounds__(256) void k_mgemm(
    const float* __restrict__ p1, const float* __restrict__ q2,
    const float* __restrict__ ip1, const float* __restrict__ iq2,
    const float* __restrict__ p2, const float* __restrict__ q1,
    const float* __restrict__ ip2, const float* __restrict__ iq1,
    float* __restrict__ Ma, float* __restrict__ Mb) {
    const int mec = blockIdx.z >> 3;
    const int kz = blockIdx.z & 7;
    const float* P = mec ? p2 : p1;
    const float* Q = mec ? q1 : q2;
    const float* iP = mec ? ip2 : ip1;
    const float* iQ = mec ? iq1 : iq2;
    float* Mout = mec ? Mb : Ma;

    __shared__ float Ps[16][68];
    __shared__ float Qs[16][68];
    const int a0 = blockIdx.y * 64, b0 = blockIdx.x * 64;
    const int i0 = kz * (B_ROWS / KS);
    const int t = threadIdx.x, tx = t & 15, ty = t >> 4;
    const int r = t >> 4, c4 = (t & 15) * 4;

    float acc[4][4] = {};
    for (int ic = 0; ic < B_ROWS / KS; ic += 16) {
        int i = i0 + ic + r;
        float w = iP[i] * iQ[i];
        float4 pv = *(const float4*)(P + (size_t)i * E_DIM + a0 + c4);
        float4 qv = *(const float4*)(Q + (size_t)i * E_DIM + b0 + c4);
        __syncthreads();
        pv.x *= w; pv.y *= w; pv.z *= w; pv.w *= w;
        *(float4*)&Ps[r][c4] = pv;
        *(float4*)&Qs[r][c4] = qv;
        __syncthreads();
#pragma unroll 4
        for (int rr = 0; rr < 16; ++rr) {
            float pa[4], qb[4];
#pragma unroll
            for (int j = 0; j < 4; ++j) { pa[j] = Ps[rr][ty * 4 + j]; qb[j] = Qs[rr][tx * 4 + j]; }
#pragma unroll
            for (int ia = 0; ia < 4; ++ia)
#pragma unroll
                for (int ib = 0; ib < 4; ++ib) acc[ia][ib] += pa[ia] * qb[ib];
        }
    }
#pragma unroll
    for (int ia = 0; ia < 4; ++ia)
#pragma unroll
        for (int ib = 0; ib < 4; ++ib)
            atomicAdd(&Mout[(size_t)(a0 + ty * 4 + ia) * E_DIM + b0 + tx * 4 + ib],
                      acc[ia][ib]);
}

// M2 = M*M (256x256). grid (16,16,2) block 256.
__global__ void k_m2(const float* __restrict__ Ma, const float* __restrict__ Mb,
                     float* __restrict__ M2a, float* __restrict__ M2b) {
    const float* M = blockIdx.z ? Mb : Ma;
    float* M2 = blockIdx.z ? M2b : M2a;
    int b = blockIdx.x * 16 + (threadIdx.x & 15);
    int a = blockIdx.y * 16 + (threadIdx.x >> 4);
    float s = 0.f;
    for (int k = 0; k < E_DIM; ++k) s += M[a * E_DIM + k] * M[k * E_DIM + b];
    M2[a * E_DIM + b] = s;
}

// Traces + final combine. 1 block, 1024 threads.
__global__ __launch_bounds__(1024) void k_traces(
    const float* __restrict__ Ma, const float* __restrict__ M2a,
    const float* __restrict__ Mb, const float* __restrict__ M2b,
    const float* __restrict__ lam, float* __restrict__ out) {
    const int t = threadIdx.x;
    float lamv = lam[0];
    float il = 1.f / lamv;
    // sum = t1/l - t2/(2 l^2) + t3/(3 l^3) - t4/(4 l^4)
    float c1 = il, c2 = -0.5f * il * il, c3 = il * il * il * (1.f / 3.f),
          c4 = -0.25f * il * il * il * il;
    float s = 0.f;
    for (int m = 0; m < 2; ++m) {
        const float* M = m ? Mb : Ma;
        const float* M2 = m ? M2b : M2a;
        float t1 = 0.f, t2 = 0.f, t3 = 0.f, t4 = 0.f;
        for (int idx = t; idx < E_DIM * E_DIM; idx += 1024) {
            int i = idx >> 8, j = idx & 255;
            float mij = M[idx], mji = M[j * E_DIM + i];
            float m2ij = M2[idx], m2ji = M2[j * E_DIM + i];
            if (i == j) t1 += mij;
            t2 += mij * mji;
            t3 += m2ij * mji;
            t4 += m2ij * m2ji;
        }
        s += t1 * c1 + t2 * c2 + t3 * c3 + t4 * c4;
    }
#pragma unroll
    for (int o = 32; o; o >>= 1) s += __shfl_down(s, o);
    __shared__ float red[16];
    if ((t & 63) == 0) red[t >> 6] = s;
    __syncthreads();
    if (t < 16) {
        float v = red[t];
#pragma unroll
        for (int o = 8; o; o >>= 1) v += __shfl_down(v, o);
        if (t == 0) out[0] = -0.5f * lamv * v * (1.f / B_ROWS);
    }
}

// ---------------------------------------------------------------------------
extern "C" void kernel_launch(void* const* d_in, const int* in_sizes, int n_in,
                              void* d_out, int out_size, void* d_ws, size_t ws_size,
                              hipStream_t stream) {
    const float* z1 = (const float*)d_in[0];
    const float* z2 = (const float*)d_in[1];
    const float* p1 = (const float*)d_in[2];
    const float* p2 = (const float*)d_in[3];
    const float* W1 = (const float*)d_in[4];
    const float* gamma = (const float*)d_in[5];
    const float* beta = (const float*)d_in[6];
    const float* W2 = (const float*)d_in[7];
    const float* b2 = (const float*)d_in[8];
    const float* lam = (const float*)d_in[9];
    float* out = (float*)d_out;
    char* ws = (char*)d_ws;

    // workspace layout (~89.2 MB)
    size_t off = 0;
    auto alloc = [&](size_t bytes) { size_t o = off; off += (bytes + 255) & ~(size_t)255; return o; };
    unsigned short* W1T = (unsigned short*)(ws + alloc((size_t)E_DIM * H_DIM * 2));  // [H,E] bf16
    unsigned short* W2T = (unsigned short*)(ws + alloc((size_t)H_DIM * E_DIM * 2));  // [E,H] bf16
    unsigned short* zb  = (unsigned short*)(ws + alloc((size_t)B_ROWS * E_DIM * 2));
    unsigned short* h   = (unsigned short*)(ws + alloc((size_t)B_ROWS * H_DIM * 2));
    float* q1 = (float*)(ws + alloc((size_t)B_ROWS * E_DIM * 4));
    float* q2 = (float*)(ws + alloc((size_t)B_ROWS * E_DIM * 4));
    float* colsum   = (float*)(ws + alloc(H_DIM * 4));
    float* colsumsq = (float*)(ws + alloc(H_DIM * 4));
    float* scale = (float*)(ws + alloc(H_DIM * 4));
    float* shift = (float*)(ws + alloc(H_DIM * 4));
    float* invp1 = (float*)(ws + alloc(B_ROWS * 4));
    float* invp2 = (float*)(ws + alloc(B_ROWS * 4));
    float* invq1 = (float*)(ws + alloc(B_ROWS * 4));
    float* invq2 = (float*)(ws + alloc(B_ROWS * 4));
    float* Ma  = (float*)(ws + alloc((size_t)E_DIM * E_DIM * 4));
    float* Mb  = (float*)(ws + alloc((size_t)E_DIM * E_DIM * 4));
    float* M2a = (float*)(ws + alloc((size_t)E_DIM * E_DIM * 4));
    float* M2b = (float*)(ws + alloc((size_t)E_DIM * E_DIM * 4));

    // weight transposes (k-contiguous operands for MFMA)
    k_transpose_cast<<<dim3(H_DIM / 32, E_DIM / 32), 256, 0, stream>>>(W1, W1T, E_DIM, H_DIM);
    k_transpose_cast<<<dim3(E_DIM / 32, H_DIM / 32), 256, 0, stream>>>(W2, W2T, H_DIM, E_DIM);

    const float* zs[2] = {z1, z2};
    float* qs[2] = {q1, q2};
    for (int v = 0; v < 2; ++v) {
        k_cast_bf16<<<dim3(B_ROWS * E_DIM / 4 / 256), 256, 0, stream>>>(zs[v], zb, B_ROWS * E_DIM / 4);
        // h = z @ W1
        k_gemm_bt<128, 128, true, false><<<dim3(H_DIM / 128, B_ROWS / 128), 256, 0, stream>>>(
            zb, W1T, h, nullptr, B_ROWS, H_DIM, E_DIM);
        hipMemsetAsync(colsum, 0, H_DIM * 2 * sizeof(float), stream);  // colsum+colsumsq contiguous
        k_colstats<<<dim3(H_DIM / 256, B_ROWS / 128), 256, 0, stream>>>(h, colsum, colsumsq);
        k_bnprep<<<dim3(H_DIM / 256), 256, 0, stream>>>(colsum, colsumsq, gamma, beta, scale, shift);
        k_bnrelu<<<dim3((size_t)B_ROWS * H_DIM / 8 / 256), 256, 0, stream>>>(h, scale, shift);
        // q = relu(bn(h)) @ W2 + b2
        k_gemm_bt<64, 128, false, true><<<dim3(E_DIM / 128, B_ROWS / 64), 256, 0, stream>>>(
            h, W2T, qs[v], b2, B_ROWS, E_DIM, H_DIM);
    }

    k_rownorm4<<<dim3(B_ROWS / 4, 4), 256, 0, stream>>>(p1, p2, q1, q2, invp1, invp2, invq1, invq2);

    hipMemsetAsync(Ma, 0, (size_t)E_DIM * E_DIM * 2 * sizeof(float), stream);  // Ma+Mb contiguous
    k_mgemm<<<dim3(4, 4, 2 * KS), 256, 0, stream>>>(p1, q2, invp1, invq2,
                                                    p2, q1, invp2, invq1, Ma, Mb);
    k_m2<<<dim3(16, 16, 2), 256, 0, stream>>>(Ma, Mb, M2a, M2b);
    k_traces<<<dim3(1), 1024, 0, stream>>>(Ma, M2a, Mb, M2b, lam, out);
}

// Round 2
// 452.644 us; speedup vs baseline: 1.3486x; 1.3486x over previous
//
#include <hip/hip_runtime.h>

// Problem constants (fixed by reference)
#define B_ROWS 8192
#define E_DIM  256
#define H_DIM  4096

typedef __attribute__((ext_vector_type(8))) short short8;
typedef __attribute__((ext_vector_type(4))) float f32x4;

typedef __attribute__((address_space(1))) const void* gas1_t;
typedef __attribute__((address_space(3))) void*       las3_t;

__device__ __forceinline__ float b2f(unsigned short s) {
    return __uint_as_float(((unsigned)s) << 16);
}
__device__ __forceinline__ unsigned short f2b(float f) {
    unsigned u = __float_as_uint(f);
    u += 0x7fffu + ((u >> 16) & 1u);   // RNE
    return (unsigned short)(u >> 16);
}

// ---------------------------------------------------------------------------
// Transpose + cast f32 [R,C] -> bf16 [C,R]   (makes W k-contiguous for MFMA)
// grid (C/32, R/32), block 256
__global__ void k_transpose_cast(const float* __restrict__ in,
                                 unsigned short* __restrict__ out,
                                 int R, int C) {
    __shared__ float tile[32][33];
    const int c0 = blockIdx.x * 32, r0 = blockIdx.y * 32;
    const int tx = threadIdx.x & 31, ty = threadIdx.x >> 5;  // ty 0..7
#pragma unroll
    for (int j = 0; j < 4; ++j)
        tile[ty * 4 + j][tx] = in[(size_t)(r0 + ty * 4 + j) * C + c0 + tx];
    __syncthreads();
#pragma unroll
    for (int j = 0; j < 4; ++j)
        out[(size_t)(c0 + ty * 4 + j) * R + r0 + tx] = f2b(tile[tx][ty * 4 + j]);
}

// ---------------------------------------------------------------------------
// Cast f32 -> bf16, 4 elems/thread. grid n/(4*256)
__global__ void k_cast_bf16(const float* __restrict__ in,
                            unsigned short* __restrict__ out, int n4) {
    int i = blockIdx.x * blockDim.x + threadIdx.x;
    if (i < n4) {
        float4 v = ((const float4*)in)[i];
        ushort4 o;
        o.x = f2b(v.x); o.y = f2b(v.y); o.z = f2b(v.z); o.w = f2b(v.w);
        ((ushort4*)out)[i] = o;
    }
}

// ---------------------------------------------------------------------------
// bf16 MFMA GEMM: C[M,N] = A[M,K] * Bt[N,K]^T  (both operands k-contiguous)
// m97-style: BK=32, 4 waves as 2x2, global_load_lds width 16, single buffer.
// ATOMIC: split-K over gridDim.z, fp32 atomicAdd epilogue (C must be zeroed);
//         bias added by the blockIdx.z==0 chunk only.
template <int BM, int BN, bool OUT_BF16, bool ADD_BIAS, bool ATOMIC>
__global__ __launch_bounds__(256) void k_gemm_bt(
    const unsigned short* __restrict__ A, const unsigned short* __restrict__ Bt,
    void* __restrict__ Cout, const float* __restrict__ bias,
    int M, int N, int K) {
    constexpr int BK = 32;
    constexpr int MI = BM / 32, NI = BN / 32;
    __shared__ __align__(16) short As[BM * BK];
    __shared__ __align__(16) short Bs[BN * BK];

    const int t = threadIdx.x;
    const int lane = t & 63, wv = t >> 6;
    const int wr = wv >> 1, wc = wv & 1;
    const int l15 = lane & 15, quad = lane >> 4;
    const int m0 = blockIdx.y * BM, n0 = blockIdx.x * BN;

    const int Kc = K / gridDim.z;
    const int kbeg = blockIdx.z * Kc, kend = kbeg + Kc;

    f32x4 acc[MI][NI] = {};

    for (int k0 = kbeg; k0 < kend; k0 += BK) {
        // stage A tile: BM rows x 32 k (64B/row), 16B per lane
#pragma unroll
        for (int q = 0; q < (BM * 4) / 256; ++q) {
            int u = q * 256 + t;
            const short* gp = (const short*)A + (size_t)(m0 + (u >> 2)) * K + k0 + (u & 3) * 8;
            short* lp = As + (size_t)(q * 256 + (wv << 6)) * 8;  // wave-uniform base
            __builtin_amdgcn_global_load_lds((gas1_t)gp, (las3_t)lp, 16, 0, 0);
        }
#pragma unroll
        for (int q = 0; q < (BN * 4) / 256; ++q) {
            int u = q * 256 + t;
            const short* gp = (const short*)Bt + (size_t)(n0 + (u >> 2)) * K + k0 + (u & 3) * 8;
            short* lp = Bs + (size_t)(q * 256 + (wv << 6)) * 8;
            __builtin_amdgcn_global_load_lds((gas1_t)gp, (las3_t)lp, 16, 0, 0);
        }
        __syncthreads();

        short8 af[MI], bfr[NI];
#pragma unroll
        for (int mi = 0; mi < MI; ++mi)
            af[mi] = *(const short8*)(As + (wr * (BM / 2) + mi * 16 + l15) * BK + quad * 8);
#pragma unroll
        for (int ni = 0; ni < NI; ++ni)
            bfr[ni] = *(const short8*)(Bs + (wc * (BN / 2) + ni * 16 + l15) * BK + quad * 8);
#pragma unroll
        for (int mi = 0; mi < MI; ++mi)
#pragma unroll
            for (int ni = 0; ni < NI; ++ni)
                acc[mi][ni] = __builtin_amdgcn_mfma_f32_16x16x32_bf16(
                    af[mi], bfr[ni], acc[mi][ni], 0, 0, 0);
        __syncthreads();
    }

    // epilogue: C/D layout col=lane&15, row=quad*4+reg (measured m89)
#pragma unroll
    for (int mi = 0; mi < MI; ++mi)
#pragma unroll
        for (int ni = 0; ni < NI; ++ni)
#pragma unroll
            for (int r = 0; r < 4; ++r) {
                int row = m0 + wr * (BM / 2) + mi * 16 + quad * 4 + r;
                int col = n0 + wc * (BN / 2) + ni * 16 + l15;
                float v = acc[mi][ni][r];
                if (ATOMIC) {
                    if (ADD_BIAS && blockIdx.z == 0) v += bias[col];
                    atomicAdd(&((float*)Cout)[(size_t)row * N + col], v);
                } else {
                    if (ADD_BIAS) v += bias[col];
                    if (OUT_BF16)
                        ((unsigned short*)Cout)[(size_t)row * N + col] = f2b(v);
                    else
                        ((float*)Cout)[(size_t)row * N + col] = v;
                }
            }
}

// ---------------------------------------------------------------------------
// Column sums / sumsq of bf16 h [B_ROWS, H_DIM]. grid (16,64) block 256.
__global__ void k_colstats(const unsigned short* __restrict__ h,
                           float* __restrict__ sum, float* __restrict__ sumsq) {
    const int col = blockIdx.x * 256 + threadIdx.x;
    const int r0 = blockIdx.y * 128;
    float s = 0.f, s2 = 0.f;
    for (int r = 0; r < 128; ++r) {
        float v = b2f(h[(size_t)(r0 + r) * H_DIM + col]);
        s += v; s2 += v * v;
    }
    atomicAdd(&sum[col], s);
    atomicAdd(&sumsq[col], s2);
}

// BN scale/shift: scale = gamma*rsqrt(var+eps), shift = beta - mu*scale
__global__ void k_bnprep(const float* __restrict__ sum, const float* __restrict__ sumsq,
                         const float* __restrict__ gamma, const float* __restrict__ beta,
                         float* __restrict__ scale, float* __restrict__ shift) {
    int j = blockIdx.x * 256 + threadIdx.x;
    float mu = sum[j] * (1.f / B_ROWS);
    float var = sumsq[j] * (1.f / B_ROWS) - mu * mu;
    float sc = gamma[j] * rsqrtf(var + 1e-5f);
    scale[j] = sc;
    shift[j] = beta[j] - mu * sc;
}

// h := relu(h*scale + shift), 8 bf16 per thread. grid B*H/8/256
__global__ void k_bnrelu(unsigned short* __restrict__ h,
                         const float* __restrict__ scale,
                         const float* __restrict__ shift) {
    size_t i8 = (size_t)blockIdx.x * 256 + threadIdx.x;
    int c0 = (int)((i8 * 8) & (H_DIM - 1));
    uint4 d = ((uint4*)h)[i8];
    unsigned short* u = (unsigned short*)&d;
#pragma unroll
    for (int j = 0; j < 8; ++j) {
        float v = b2f(u[j]) * scale[c0 + j] + shift[c0 + j];
        u[j] = f2b(fmaxf(v, 0.f));
    }
    ((uint4*)h)[i8] = d;
}

// ---------------------------------------------------------------------------
// Row inverse-norms of 4 [B,256] f32 arrays. grid (B/4, 4), 1 wave/row.
__global__ void k_rownorm4(const float* __restrict__ a0, const float* __restrict__ a1,
                           const float* __restrict__ a2, const float* __restrict__ a3,
                           float* __restrict__ o0, float* __restrict__ o1,
                           float* __restrict__ o2, float* __restrict__ o3) {
    int which = blockIdx.y;
    const float* x = which == 0 ? a0 : which == 1 ? a1 : which == 2 ? a2 : a3;
    float* inv = which == 0 ? o0 : which == 1 ? o1 : which == 2 ? o2 : o3;
    int row = blockIdx.x * 4 + (threadIdx.x >> 6);
    int lane = threadIdx.x & 63;
    float4 v = ((const float4*)(x + (size_t)row * E_DIM))[lane];
    float s = v.x * v.x + v.y * v.y + v.z * v.z + v.w * v.w;
#pragma unroll
    for (int o = 32; o; o >>= 1) s += __shfl_down(s, o);
    if (lane == 0) inv[row] = 1.f / fmaxf(sqrtf(s), 1e-12f);
}

// ---------------------------------------------------------------------------
// Gram: Mout[a][b] += sum_i P[i,a]*Q[i,b]*invP[i]*invQ[i]
// grid (4,4,16): z = mec*8 + kchunk (chunks of 1024 rows). atomic split-K.
#define KS 8
__global__ __launch_bounds__(256) void k_mgemm(
    const float* __restrict__ p1, const float* __restrict__ q2,
    const float* __restrict__ ip1, const float* __restrict__ iq2,
    const float* __restrict__ p2, const float* __restrict__ q1,
    const float* __restrict__ ip2, const float* __restrict__ iq1,
    float* __restrict__ Ma, float* __restrict__ Mb) {
    const int mec = blockIdx.z >> 3;
    const int kz = blockIdx.z & 7;
    const float* P = mec ? p2 : p1;
    const float* Q = mec ? q1 : q2;
    const float* iP = mec ? ip2 : ip1;
    const float* iQ = mec ? iq1 : iq2;
    float* Mout = mec ? Mb : Ma;

    __shared__ float Ps[16][68];
    __shared__ float Qs[16][68];
    const int a0 = blockIdx.y * 64, b0 = blockIdx.x * 64;
    const int i0 = kz * (B_ROWS / KS);
    const int t = threadIdx.x, tx = t & 15, ty = t >> 4;
    const int r = t >> 4, c4 = (t & 15) * 4;

    float acc[4][4] = {};
    for (int ic = 0; ic < B_ROWS / KS; ic += 16) {
        int i = i0 + ic + r;
        float w = iP[i] * iQ[i];
        float4 pv = *(const float4*)(P + (size_t)i * E_DIM + a0 + c4);
        float4 qv = *(const float4*)(Q + (size_t)i * E_DIM + b0 + c4);
        __syncthreads();
        pv.x *= w; pv.y *= w; pv.z *= w; pv.w *= w;
        *(float4*)&Ps[r][c4] = pv;
        *(float4*)&Qs[r][c4] = qv;
        __syncthreads();
#pragma unroll 4
        for (int rr = 0; rr < 16; ++rr) {
            float pa[4], qb[4];
#pragma unroll
            for (int j = 0; j < 4; ++j) { pa[j] = Ps[rr][ty * 4 + j]; qb[j] = Qs[rr][tx * 4 + j]; }
#pragma unroll
            for (int ia = 0; ia < 4; ++ia)
#pragma unroll
                for (int ib = 0; ib < 4; ++ib) acc[ia][ib] += pa[ia] * qb[ib];
        }
    }
#pragma unroll
    for (int ia = 0; ia < 4; ++ia)
#pragma unroll
        for (int ib = 0; ib < 4; ++ib)
            atomicAdd(&Mout[(size_t)(a0 + ty * 4 + ia) * E_DIM + b0 + tx * 4 + ib],
                      acc[ia][ib]);
}

// M2 = M*M (256x256). grid (16,16,2) block 256.
__global__ void k_m2(const float* __restrict__ Ma, const float* __restrict__ Mb,
                     float* __restrict__ M2a, float* __restrict__ M2b) {
    const float* M = blockIdx.z ? Mb : Ma;
    float* M2 = blockIdx.z ? M2b : M2a;
    int b = blockIdx.x * 16 + (threadIdx.x & 15);
    int a = blockIdx.y * 16 + (threadIdx.x >> 4);
    float s = 0.f;
    for (int k = 0; k < E_DIM; ++k) s += M[a * E_DIM + k] * M[k * E_DIM + b];
    M2[a * E_DIM + b] = s;
}

// ---------------------------------------------------------------------------
// Traces, tiled multi-block: grid (8,8,2), block 256. 32x32 tiles of M/M2 and
// their transposed tiles staged in LDS (all-coalesced loads), per-block
// reduce, one atomicAdd into pre-zeroed out[0].
__global__ __launch_bounds__(256) void k_traces2(
    const float* __restrict__ Ma, const float* __restrict__ M2a,
    const float* __restrict__ Mb, const float* __restrict__ M2b,
    const float* __restrict__ lam, float* __restrict__ out) {
    const float* M  = blockIdx.z ? Mb  : Ma;
    const float* M2 = blockIdx.z ? M2b : M2a;
    const int i0 = blockIdx.y * 32, j0 = blockIdx.x * 32;
    const int t = threadIdx.x, col = t & 31, row = t >> 5;  // row 0..7

    __shared__ float A[32][33], Bt[32][33], A2[32][33], B2[32][33];
#pragma unroll
    for (int r = 0; r < 4; ++r) {
        int rr = r * 8 + row;
        A [rr][col] = M [(i0 + rr) * E_DIM + j0 + col];
        Bt[rr][col] = M [(j0 + rr) * E_DIM + i0 + col];
        A2[rr][col] = M2[(i0 + rr) * E_DIM + j0 + col];
        B2[rr][col] = M2[(j0 + rr) * E_DIM + i0 + col];
    }
    __syncthreads();

    float lamv = lam[0];
    float il = 1.f / lamv;
    float F = -0.5f * lamv * (1.f / B_ROWS);  // -0.5*lam/B
    float c1 = F * il;
    float c2 = -F * 0.5f * il * il;
    float c3 = F * (1.f / 3.f) * il * il * il;
    float c4 = -F * 0.25f * il * il * il * il;

    float s = 0.f;
#pragma unroll
    for (int r = 0; r < 4; ++r) {
        int rr = r * 8 + row;
        float mij = A[rr][col], mji = Bt[col][rr];
        float m2ij = A2[rr][col], m2ji = B2[col][rr];
        s += c2 * mij * mji + c3 * m2ij * mji + c4 * m2ij * m2ji;
        if (i0 + rr == j0 + col) s += c1 * mij;
    }
#pragma unroll
    for (int o = 32; o; o >>= 1) s += __shfl_down(s, o);
    __shared__ float red[4];
    if ((t & 63) == 0) red[t >> 6] = s;
    __syncthreads();
    if (t == 0) atomicAdd(out, red[0] + red[1] + red[2] + red[3]);
}

// ---------------------------------------------------------------------------
extern "C" void kernel_launch(void* const* d_in, const int* in_sizes, int n_in,
                              void* d_out, int out_size, void* d_ws, size_t ws_size,
                              hipStream_t stream) {
    const float* z1 = (const float*)d_in[0];
    const float* z2 = (const float*)d_in[1];
    const float* p1 = (const float*)d_in[2];
    const float* p2 = (const float*)d_in[3];
    const float* W1 = (const float*)d_in[4];
    const float* gamma = (const float*)d_in[5];
    const float* beta = (const float*)d_in[6];
    const float* W2 = (const float*)d_in[7];
    const float* b2 = (const float*)d_in[8];
    const float* lam = (const float*)d_in[9];
    float* out = (float*)d_out;
    char* ws = (char*)d_ws;

    // workspace layout (~89.2 MB)
    size_t off = 0;
    auto alloc = [&](size_t bytes) { size_t o = off; off += (bytes + 255) & ~(size_t)255; return o; };
    unsigned short* W1T = (unsigned short*)(ws + alloc((size_t)E_DIM * H_DIM * 2));  // [H,E] bf16
    unsigned short* W2T = (unsigned short*)(ws + alloc((size_t)H_DIM * E_DIM * 2));  // [E,H] bf16
    unsigned short* zb  = (unsigned short*)(ws + alloc((size_t)B_ROWS * E_DIM * 2));
    unsigned short* h   = (unsigned short*)(ws + alloc((size_t)B_ROWS * H_DIM * 2));
    float* q1 = (float*)(ws + alloc((size_t)B_ROWS * E_DIM * 4));
    float* q2 = (float*)(ws + alloc((size_t)B_ROWS * E_DIM * 4));
    float* colsum   = (float*)(ws + alloc(H_DIM * 4));
    float* colsumsq = (float*)(ws + alloc(H_DIM * 4));
    float* scale = (float*)(ws + alloc(H_DIM * 4));
    float* shift = (float*)(ws + alloc(H_DIM * 4));
    float* invp1 = (float*)(ws + alloc(B_ROWS * 4));
    float* invp2 = (float*)(ws + alloc(B_ROWS * 4));
    float* invq1 = (float*)(ws + alloc(B_ROWS * 4));
    float* invq2 = (float*)(ws + alloc(B_ROWS * 4));
    float* Ma  = (float*)(ws + alloc((size_t)E_DIM * E_DIM * 4));
    float* Mb  = (float*)(ws + alloc((size_t)E_DIM * E_DIM * 4));
    float* M2a = (float*)(ws + alloc((size_t)E_DIM * E_DIM * 4));
    float* M2b = (float*)(ws + alloc((size_t)E_DIM * E_DIM * 4));

    // zero the accumulation targets (d_ws/d_out are poisoned before each call)
    hipMemsetAsync(out, 0, sizeof(float), stream);
    hipMemsetAsync(q1, 0, (size_t)2 * B_ROWS * E_DIM * sizeof(float), stream);  // q1+q2 contiguous

    // weight transposes (k-contiguous operands for MFMA)
    k_transpose_cast<<<dim3(H_DIM / 32, E_DIM / 32), 256, 0, stream>>>(W1, W1T, E_DIM, H_DIM);
    k_transpose_cast<<<dim3(E_DIM / 32, H_DIM / 32), 256, 0, stream>>>(W2, W2T, H_DIM, E_DIM);

    const float* zs[2] = {z1, z2};
    float* qs[2] = {q1, q2};
    for (int v = 0; v < 2; ++v) {
        k_cast_bf16<<<dim3(B_ROWS * E_DIM / 4 / 256), 256, 0, stream>>>(zs[v], zb, B_ROWS * E_DIM / 4);
        // h = z @ W1
        k_gemm_bt<128, 128, true, false, false><<<dim3(H_DIM / 128, B_ROWS / 128), 256, 0, stream>>>(
            zb, W1T, h, nullptr, B_ROWS, H_DIM, E_DIM);
        hipMemsetAsync(colsum, 0, H_DIM * 2 * sizeof(float), stream);  // colsum+colsumsq contiguous
        k_colstats<<<dim3(H_DIM / 256, B_ROWS / 128), 256, 0, stream>>>(h, colsum, colsumsq);
        k_bnprep<<<dim3(H_DIM / 256), 256, 0, stream>>>(colsum, colsumsq, gamma, beta, scale, shift);
        k_bnrelu<<<dim3((size_t)B_ROWS * H_DIM / 8 / 256), 256, 0, stream>>>(h, scale, shift);
        // q = relu(bn(h)) @ W2 + b2   — split-K x4, atomic fp32 accumulate
        k_gemm_bt<64, 128, false, true, true><<<dim3(E_DIM / 128, B_ROWS / 64, 4), 256, 0, stream>>>(
            h, W2T, qs[v], b2, B_ROWS, E_DIM, H_DIM);
    }

    k_rownorm4<<<dim3(B_ROWS / 4, 4), 256, 0, stream>>>(p1, p2, q1, q2, invp1, invp2, invq1, invq2);

    hipMemsetAsync(Ma, 0, (size_t)E_DIM * E_DIM * 2 * sizeof(float), stream);  // Ma+Mb contiguous
    k_mgemm<<<dim3(4, 4, 2 * KS), 256, 0, stream>>>(p1, q2, invp1, invq2,
                                                    p2, q1, invp2, invq1, Ma, Mb);
    k_m2<<<dim3(16, 16, 2), 256, 0, stream>>>(Ma, Mb, M2a, M2b);
    k_traces2<<<dim3(8, 8, 2), 256, 0, stream>>>(Ma, M2a, Mb, M2b, lam, out);
}

// Round 3
// 386.323 us; speedup vs baseline: 1.5801x; 1.1717x over previous
//
#include <hip/hip_runtime.h>

// Problem constants (fixed by reference)
#define B_ROWS 8192
#define E_DIM  256
#define H_DIM  4096

typedef __attribute__((ext_vector_type(8))) short short8;
typedef __attribute__((ext_vector_type(4))) float f32x4;

typedef __attribute__((address_space(1))) const void* gas1_t;
typedef __attribute__((address_space(3))) void*       las3_t;

__device__ __forceinline__ float b2f(unsigned short s) {
    return __uint_as_float(((unsigned)s) << 16);
}
__device__ __forceinline__ unsigned short f2b(float f) {
    unsigned u = __float_as_uint(f);
    u += 0x7fffu + ((u >> 16) & 1u);   // RNE
    return (unsigned short)(u >> 16);
}

// ---------------------------------------------------------------------------
// Transpose + cast f32 [R,C] -> bf16 [C,R]   (makes W k-contiguous for MFMA)
// grid (C/32, R/32), block 256
__global__ void k_transpose_cast(const float* __restrict__ in,
                                 unsigned short* __restrict__ out,
                                 int R, int C) {
    __shared__ float tile[32][33];
    const int c0 = blockIdx.x * 32, r0 = blockIdx.y * 32;
    const int tx = threadIdx.x & 31, ty = threadIdx.x >> 5;  // ty 0..7
#pragma unroll
    for (int j = 0; j < 4; ++j)
        tile[ty * 4 + j][tx] = in[(size_t)(r0 + ty * 4 + j) * C + c0 + tx];
    __syncthreads();
#pragma unroll
    for (int j = 0; j < 4; ++j)
        out[(size_t)(c0 + ty * 4 + j) * R + r0 + tx] = f2b(tile[tx][ty * 4 + j]);
}

// ---------------------------------------------------------------------------
// Cast f32 -> bf16, 4 elems/thread. grid n/(4*256)
__global__ void k_cast_bf16(const float* __restrict__ in,
                            unsigned short* __restrict__ out, int n4) {
    int i = blockIdx.x * blockDim.x + threadIdx.x;
    if (i < n4) {
        float4 v = ((const float4*)in)[i];
        ushort4 o;
        o.x = f2b(v.x); o.y = f2b(v.y); o.z = f2b(v.z); o.w = f2b(v.w);
        ((ushort4*)out)[i] = o;
    }
}

// ---------------------------------------------------------------------------
// bf16 MFMA GEMM: C[M,N] = A[M,K] * Bt[N,K]^T  (both operands k-contiguous)
// m97-style: BK=32, 4 waves as 2x2, global_load_lds width 16, single buffer.
// ATOMIC: split-K over gridDim.z, fp32 atomicAdd epilogue (C must be zeroed);
//         bias added by the blockIdx.z==0 chunk only.
// COLSTATS: also accumulate per-column sum/sumsq of C into cs/cs2 (pre-zeroed)
template <int BM, int BN, bool OUT_BF16, bool ADD_BIAS, bool ATOMIC, bool COLSTATS>
__global__ __launch_bounds__(256) void k_gemm_bt(
    const unsigned short* __restrict__ A, const unsigned short* __restrict__ Bt,
    void* __restrict__ Cout, const float* __restrict__ bias,
    float* __restrict__ cs, float* __restrict__ cs2,
    int M, int N, int K) {
    constexpr int BK = 32;
    constexpr int MI = BM / 32, NI = BN / 32;
    __shared__ __align__(16) short As[BM * BK];
    __shared__ __align__(16) short Bs[BN * BK];

    const int t = threadIdx.x;
    const int lane = t & 63, wv = t >> 6;
    const int wr = wv >> 1, wc = wv & 1;
    const int l15 = lane & 15, quad = lane >> 4;
    const int m0 = blockIdx.y * BM, n0 = blockIdx.x * BN;

    const int Kc = K / gridDim.z;
    const int kbeg = blockIdx.z * Kc, kend = kbeg + Kc;

    f32x4 acc[MI][NI] = {};

    for (int k0 = kbeg; k0 < kend; k0 += BK) {
        // stage A tile: BM rows x 32 k (64B/row), 16B per lane
#pragma unroll
        for (int q = 0; q < (BM * 4) / 256; ++q) {
            int u = q * 256 + t;
            const short* gp = (const short*)A + (size_t)(m0 + (u >> 2)) * K + k0 + (u & 3) * 8;
            short* lp = As + (size_t)(q * 256 + (wv << 6)) * 8;  // wave-uniform base
            __builtin_amdgcn_global_load_lds((gas1_t)gp, (las3_t)lp, 16, 0, 0);
        }
#pragma unroll
        for (int q = 0; q < (BN * 4) / 256; ++q) {
            int u = q * 256 + t;
            const short* gp = (const short*)Bt + (size_t)(n0 + (u >> 2)) * K + k0 + (u & 3) * 8;
            short* lp = Bs + (size_t)(q * 256 + (wv << 6)) * 8;
            __builtin_amdgcn_global_load_lds((gas1_t)gp, (las3_t)lp, 16, 0, 0);
        }
        __syncthreads();

        short8 af[MI], bfr[NI];
#pragma unroll
        for (int mi = 0; mi < MI; ++mi)
            af[mi] = *(const short8*)(As + (wr * (BM / 2) + mi * 16 + l15) * BK + quad * 8);
#pragma unroll
        for (int ni = 0; ni < NI; ++ni)
            bfr[ni] = *(const short8*)(Bs + (wc * (BN / 2) + ni * 16 + l15) * BK + quad * 8);
#pragma unroll
        for (int mi = 0; mi < MI; ++mi)
#pragma unroll
            for (int ni = 0; ni < NI; ++ni)
                acc[mi][ni] = __builtin_amdgcn_mfma_f32_16x16x32_bf16(
                    af[mi], bfr[ni], acc[mi][ni], 0, 0, 0);
        __syncthreads();
    }

    // epilogue: C/D layout col=lane&15, row=quad*4+reg (measured m89)
#pragma unroll
    for (int ni = 0; ni < NI; ++ni) {
        float s = 0.f, s2 = 0.f;
#pragma unroll
        for (int mi = 0; mi < MI; ++mi)
#pragma unroll
            for (int r = 0; r < 4; ++r) {
                int row = m0 + wr * (BM / 2) + mi * 16 + quad * 4 + r;
                int col = n0 + wc * (BN / 2) + ni * 16 + l15;
                float v = acc[mi][ni][r];
                if (ATOMIC) {
                    if (ADD_BIAS && blockIdx.z == 0) v += bias[col];
                    atomicAdd(&((float*)Cout)[(size_t)row * N + col], v);
                } else {
                    if (ADD_BIAS) v += bias[col];
                    if (OUT_BF16)
                        ((unsigned short*)Cout)[(size_t)row * N + col] = f2b(v);
                    else
                        ((float*)Cout)[(size_t)row * N + col] = v;
                }
                if (COLSTATS) { s += v; s2 += v * v; }
            }
        if (COLSTATS) {
            // reduce over quads (rows) within the wave: lanes l15 hold col totals
            s  += __shfl_xor(s, 16);  s  += __shfl_xor(s, 32);
            s2 += __shfl_xor(s2, 16); s2 += __shfl_xor(s2, 32);
            if (quad == 0) {
                int col = n0 + wc * (BN / 2) + ni * 16 + l15;
                atomicAdd(&cs[col], s);
                atomicAdd(&cs2[col], s2);
            }
        }
    }
}

// BN scale/shift: scale = gamma*rsqrt(var+eps), shift = beta - mu*scale
__global__ void k_bnprep(const float* __restrict__ sum, const float* __restrict__ sumsq,
                         const float* __restrict__ gamma, const float* __restrict__ beta,
                         float* __restrict__ scale, float* __restrict__ shift) {
    int j = blockIdx.x * 256 + threadIdx.x;
    float mu = sum[j] * (1.f / B_ROWS);
    float var = sumsq[j] * (1.f / B_ROWS) - mu * mu;
    float sc = gamma[j] * rsqrtf(var + 1e-5f);
    scale[j] = sc;
    shift[j] = beta[j] - mu * sc;
}

// h := relu(h*scale + shift), 8 bf16 per thread. grid B*H/8/256
__global__ void k_bnrelu(unsigned short* __restrict__ h,
                         const float* __restrict__ scale,
                         const float* __restrict__ shift) {
    size_t i8 = (size_t)blockIdx.x * 256 + threadIdx.x;
    int c0 = (int)((i8 * 8) & (H_DIM - 1));
    uint4 d = ((uint4*)h)[i8];
    unsigned short* u = (unsigned short*)&d;
#pragma unroll
    for (int j = 0; j < 8; ++j) {
        float v = b2f(u[j]) * scale[c0 + j] + shift[c0 + j];
        u[j] = f2b(fmaxf(v, 0.f));
    }
    ((uint4*)h)[i8] = d;
}

// ---------------------------------------------------------------------------
// Row inverse-norms of 4 [B,256] f32 arrays. grid (B/4, 4), 1 wave/row.
__global__ void k_rownorm4(const float* __restrict__ a0, const float* __restrict__ a1,
                           const float* __restrict__ a2, const float* __restrict__ a3,
                           float* __restrict__ o0, float* __restrict__ o1,
                           float* __restrict__ o2, float* __restrict__ o3) {
    int which = blockIdx.y;
    const float* x = which == 0 ? a0 : which == 1 ? a1 : which == 2 ? a2 : a3;
    float* inv = which == 0 ? o0 : which == 1 ? o1 : which == 2 ? o2 : o3;
    int row = blockIdx.x * 4 + (threadIdx.x >> 6);
    int lane = threadIdx.x & 63;
    float4 v = ((const float4*)(x + (size_t)row * E_DIM))[lane];
    float s = v.x * v.x + v.y * v.y + v.z * v.z + v.w * v.w;
#pragma unroll
    for (int o = 32; o; o >>= 1) s += __shfl_down(s, o);
    if (lane == 0) inv[row] = 1.f / fmaxf(sqrtf(s), 1e-12f);
}

// ---------------------------------------------------------------------------
// Transpose + row-scale + cast: X [8192,256] f32, inv[8192] -> XT [256,8192] bf16
// grid (8, 256, 4) for the 4 arrays. block 256.
__global__ void k_tn_cast(
    const float* __restrict__ x0, const float* __restrict__ x1,
    const float* __restrict__ x2, const float* __restrict__ x3,
    const float* __restrict__ i0, const float* __restrict__ i1,
    const float* __restrict__ i2, const float* __restrict__ i3,
    unsigned short* __restrict__ o0, unsigned short* __restrict__ o1,
    unsigned short* __restrict__ o2, unsigned short* __restrict__ o3) {
    const int z = blockIdx.z;
    const float* x = z == 0 ? x0 : z == 1 ? x1 : z == 2 ? x2 : x3;
    const float* inv = z == 0 ? i0 : z == 1 ? i1 : z == 2 ? i2 : i3;
    unsigned short* out = z == 0 ? o0 : z == 1 ? o1 : z == 2 ? o2 : o3;

    __shared__ float tile[32][33];
    const int c0 = blockIdx.x * 32, r0 = blockIdx.y * 32;
    const int tx = threadIdx.x & 31, ty = threadIdx.x >> 5;
#pragma unroll
    for (int j = 0; j < 4; ++j) {
        int r = r0 + ty * 4 + j;
        tile[ty * 4 + j][tx] = x[(size_t)r * E_DIM + c0 + tx] * inv[r];
    }
    __syncthreads();
#pragma unroll
    for (int j = 0; j < 4; ++j)
        out[(size_t)(c0 + ty * 4 + j) * B_ROWS + r0 + tx] = f2b(tile[tx][ty * 4 + j]);
}

// ---------------------------------------------------------------------------
// Gram via MFMA: Mout[a,b] += sum_k AT[a,k]*BT[b,k], AT/BT bf16 [256,8192].
// BM=BN=64, BK=32, split-K x16; grid (4,4,32): z = mec*16 + kz.
#define GKS 16
__global__ __launch_bounds__(256) void k_gram(
    const unsigned short* __restrict__ p1T, const unsigned short* __restrict__ q2T,
    const unsigned short* __restrict__ p2T, const unsigned short* __restrict__ q1T,
    float* __restrict__ Ma, float* __restrict__ Mb) {
    constexpr int BK = 32;
    const int mec = blockIdx.z >> 4, kz = blockIdx.z & 15;
    const unsigned short* A = mec ? p2T : p1T;
    const unsigned short* Bt = mec ? q1T : q2T;
    float* Mout = mec ? Mb : Ma;

    __shared__ __align__(16) short As[64 * BK];
    __shared__ __align__(16) short Bs[64 * BK];

    const int t = threadIdx.x;
    const int lane = t & 63, wv = t >> 6;
    const int wr = wv >> 1, wc = wv & 1;
    const int l15 = lane & 15, quad = lane >> 4;
    const int m0 = blockIdx.y * 64, n0 = blockIdx.x * 64;
    const int kbeg = kz * (B_ROWS / GKS);

    f32x4 acc[2][2] = {};

    for (int k0 = kbeg; k0 < kbeg + B_ROWS / GKS; k0 += BK) {
        const short* gpa = (const short*)A + (size_t)(m0 + (t >> 2)) * B_ROWS + k0 + (t & 3) * 8;
        short* lpa = As + (size_t)(wv << 6) * 8;
        __builtin_amdgcn_global_load_lds((gas1_t)gpa, (las3_t)lpa, 16, 0, 0);
        const short* gpb = (const short*)Bt + (size_t)(n0 + (t >> 2)) * B_ROWS + k0 + (t & 3) * 8;
        short* lpb = Bs + (size_t)(wv << 6) * 8;
        __builtin_amdgcn_global_load_lds((gas1_t)gpb, (las3_t)lpb, 16, 0, 0);
        __syncthreads();

        short8 af[2], bfr[2];
#pragma unroll
        for (int mi = 0; mi < 2; ++mi)
            af[mi] = *(const short8*)(As + (wr * 32 + mi * 16 + l15) * BK + quad * 8);
#pragma unroll
        for (int ni = 0; ni < 2; ++ni)
            bfr[ni] = *(const short8*)(Bs + (wc * 32 + ni * 16 + l15) * BK + quad * 8);
#pragma unroll
        for (int mi = 0; mi < 2; ++mi)
#pragma unroll
            for (int ni = 0; ni < 2; ++ni)
                acc[mi][ni] = __builtin_amdgcn_mfma_f32_16x16x32_bf16(
                    af[mi], bfr[ni], acc[mi][ni], 0, 0, 0);
        __syncthreads();
    }

#pragma unroll
    for (int mi = 0; mi < 2; ++mi)
#pragma unroll
        for (int ni = 0; ni < 2; ++ni)
#pragma unroll
            for (int r = 0; r < 4; ++r) {
                int row = m0 + wr * 32 + mi * 16 + quad * 4 + r;
                int col = n0 + wc * 32 + ni * 16 + l15;
                atomicAdd(&Mout[(size_t)row * E_DIM + col], acc[mi][ni][r]);
            }
}

// M2 = M*M (256x256). grid (16,16,2) block 256.
__global__ void k_m2(const float* __restrict__ Ma, const float* __restrict__ Mb,
                     float* __restrict__ M2a, float* __restrict__ M2b) {
    const float* M = blockIdx.z ? Mb : Ma;
    float* M2 = blockIdx.z ? M2b : M2a;
    int b = blockIdx.x * 16 + (threadIdx.x & 15);
    int a = blockIdx.y * 16 + (threadIdx.x >> 4);
    float s = 0.f;
    for (int k = 0; k < E_DIM; ++k) s += M[a * E_DIM + k] * M[k * E_DIM + b];
    M2[a * E_DIM + b] = s;
}

// ---------------------------------------------------------------------------
// Traces, tiled multi-block: grid (8,8,2), block 256.
__global__ __launch_bounds__(256) void k_traces2(
    const float* __restrict__ Ma, const float* __restrict__ M2a,
    const float* __restrict__ Mb, const float* __restrict__ M2b,
    const float* __restrict__ lam, float* __restrict__ out) {
    const float* M  = blockIdx.z ? Mb  : Ma;
    const float* M2 = blockIdx.z ? M2b : M2a;
    const int i0 = blockIdx.y * 32, j0 = blockIdx.x * 32;
    const int t = threadIdx.x, col = t & 31, row = t >> 5;  // row 0..7

    __shared__ float A[32][33], Bt[32][33], A2[32][33], B2[32][33];
#pragma unroll
    for (int r = 0; r < 4; ++r) {
        int rr = r * 8 + row;
        A [rr][col] = M [(i0 + rr) * E_DIM + j0 + col];
        Bt[rr][col] = M [(j0 + rr) * E_DIM + i0 + col];
        A2[rr][col] = M2[(i0 + rr) * E_DIM + j0 + col];
        B2[rr][col] = M2[(j0 + rr) * E_DIM + i0 + col];
    }
    __syncthreads();

    float lamv = lam[0];
    float il = 1.f / lamv;
    float F = -0.5f * lamv * (1.f / B_ROWS);  // -0.5*lam/B
    float c1 = F * il;
    float c2 = -F * 0.5f * il * il;
    float c3 = F * (1.f / 3.f) * il * il * il;
    float c4 = -F * 0.25f * il * il * il * il;

    float s = 0.f;
#pragma unroll
    for (int r = 0; r < 4; ++r) {
        int rr = r * 8 + row;
        float mij = A[rr][col], mji = Bt[col][rr];
        float m2ij = A2[rr][col], m2ji = B2[col][rr];
        s += c2 * mij * mji + c3 * m2ij * mji + c4 * m2ij * m2ji;
        if (i0 + rr == j0 + col) s += c1 * mij;
    }
#pragma unroll
    for (int o = 32; o; o >>= 1) s += __shfl_down(s, o);
    __shared__ float red[4];
    if ((t & 63) == 0) red[t >> 6] = s;
    __syncthreads();
    if (t == 0) atomicAdd(out, red[0] + red[1] + red[2] + red[3]);
}

// ---------------------------------------------------------------------------
extern "C" void kernel_launch(void* const* d_in, const int* in_sizes, int n_in,
                              void* d_out, int out_size, void* d_ws, size_t ws_size,
                              hipStream_t stream) {
    const float* z1 = (const float*)d_in[0];
    const float* z2 = (const float*)d_in[1];
    const float* p1 = (const float*)d_in[2];
    const float* p2 = (const float*)d_in[3];
    const float* W1 = (const float*)d_in[4];
    const float* gamma = (const float*)d_in[5];
    const float* beta = (const float*)d_in[6];
    const float* W2 = (const float*)d_in[7];
    const float* b2 = (const float*)d_in[8];
    const float* lam = (const float*)d_in[9];
    float* out = (float*)d_out;
    char* ws = (char*)d_ws;

    // workspace layout (~89 MB)
    size_t off = 0;
    auto alloc = [&](size_t bytes) { size_t o = off; off += (bytes + 255) & ~(size_t)255; return o; };
    unsigned short* W1T = (unsigned short*)(ws + alloc((size_t)E_DIM * H_DIM * 2));  // [H,E] bf16
    unsigned short* W2T = (unsigned short*)(ws + alloc((size_t)H_DIM * E_DIM * 2));  // [E,H] bf16
    unsigned short* zb  = (unsigned short*)(ws + alloc((size_t)B_ROWS * E_DIM * 2));
    unsigned short* h   = (unsigned short*)(ws + alloc((size_t)B_ROWS * H_DIM * 2));
    float* q1 = (float*)(ws + alloc((size_t)B_ROWS * E_DIM * 4));
    float* q2 = (float*)(ws + alloc((size_t)B_ROWS * E_DIM * 4));
    float* colsum   = (float*)(ws + alloc(H_DIM * 4));
    float* colsumsq = (float*)(ws + alloc(H_DIM * 4));
    float* scale = (float*)(ws + alloc(H_DIM * 4));
    float* shift = (float*)(ws + alloc(H_DIM * 4));
    float* invp1 = (float*)(ws + alloc(B_ROWS * 4));
    float* invp2 = (float*)(ws + alloc(B_ROWS * 4));
    float* invq1 = (float*)(ws + alloc(B_ROWS * 4));
    float* invq2 = (float*)(ws + alloc(B_ROWS * 4));
    float* Ma  = (float*)(ws + alloc((size_t)E_DIM * E_DIM * 4));
    float* Mb  = (float*)(ws + alloc((size_t)E_DIM * E_DIM * 4));
    float* M2a = (float*)(ws + alloc((size_t)E_DIM * E_DIM * 4));
    float* M2b = (float*)(ws + alloc((size_t)E_DIM * E_DIM * 4));

    // transposed normalized bf16 views alias into h (free after last GEMM2)
    const size_t TSZ = (size_t)E_DIM * B_ROWS;  // 2M elements each
    unsigned short* p1T = h;
    unsigned short* q2T = h + TSZ;
    unsigned short* p2T = h + 2 * TSZ;
    unsigned short* q1T = h + 3 * TSZ;

    // zero the accumulation targets (d_ws/d_out are poisoned before each call)
    hipMemsetAsync(out, 0, sizeof(float), stream);
    hipMemsetAsync(q1, 0, (size_t)2 * B_ROWS * E_DIM * sizeof(float), stream);  // q1+q2 contiguous

    // weight transposes (k-contiguous operands for MFMA)
    k_transpose_cast<<<dim3(H_DIM / 32, E_DIM / 32), 256, 0, stream>>>(W1, W1T, E_DIM, H_DIM);
    k_transpose_cast<<<dim3(E_DIM / 32, H_DIM / 32), 256, 0, stream>>>(W2, W2T, H_DIM, E_DIM);

    const float* zs[2] = {z1, z2};
    float* qs[2] = {q1, q2};
    for (int v = 0; v < 2; ++v) {
        k_cast_bf16<<<dim3(B_ROWS * E_DIM / 4 / 256), 256, 0, stream>>>(zs[v], zb, B_ROWS * E_DIM / 4);
        hipMemsetAsync(colsum, 0, H_DIM * 2 * sizeof(float), stream);  // colsum+colsumsq contiguous
        // h = z @ W1, with fused column stats
        k_gemm_bt<128, 128, true, false, false, true>
            <<<dim3(H_DIM / 128, B_ROWS / 128), 256, 0, stream>>>(
            zb, W1T, h, nullptr, colsum, colsumsq, B_ROWS, H_DIM, E_DIM);
        k_bnprep<<<dim3(H_DIM / 256), 256, 0, stream>>>(colsum, colsumsq, gamma, beta, scale, shift);
        k_bnrelu<<<dim3((size_t)B_ROWS * H_DIM / 8 / 256), 256, 0, stream>>>(h, scale, shift);
        // q = relu(bn(h)) @ W2 + b2   — split-K x4, atomic fp32 accumulate
        k_gemm_bt<64, 128, false, true, true, false>
            <<<dim3(E_DIM / 128, B_ROWS / 64, 4), 256, 0, stream>>>(
            h, W2T, qs[v], b2, nullptr, nullptr, B_ROWS, E_DIM, H_DIM);
    }

    k_rownorm4<<<dim3(B_ROWS / 4, 4), 256, 0, stream>>>(p1, p2, q1, q2, invp1, invp2, invq1, invq2);

    // transposed, row-normalized, bf16 copies of p1,q2,p2,q1 (into h's space)
    k_tn_cast<<<dim3(E_DIM / 32, B_ROWS / 32, 4), 256, 0, stream>>>(
        p1, q2, p2, q1, invp1, invq2, invp2, invq1, p1T, q2T, p2T, q1T);

    hipMemsetAsync(Ma, 0, (size_t)E_DIM * E_DIM * 2 * sizeof(float), stream);  // Ma+Mb contiguous
    k_gram<<<dim3(4, 4, 2 * GKS), 256, 0, stream>>>(p1T, q2T, p2T, q1T, Ma, Mb);
    k_m2<<<dim3(16, 16, 2), 256, 0, stream>>>(Ma, Mb, M2a, M2b);
    k_traces2<<<dim3(8, 8, 2), 256, 0, stream>>>(Ma, M2a, Mb, M2b, lam, out);
}